// Round 7
// baseline (238.202 us; speedup 1.0000x reference)
//
#include <hip/hip_runtime.h>

typedef _Float16 f16;
typedef f16 f16x2 __attribute__((ext_vector_type(2)));
typedef f16 f16x4 __attribute__((ext_vector_type(4)));
typedef f16 f16x8 __attribute__((ext_vector_type(8)));
typedef float f32x4 __attribute__((ext_vector_type(4)));

#define NB   2
#define LL   2048
#define LQ   2048         // q tokens per scrambled batch
#define LKV  512          // unique kv tokens per scrambled batch
#define DD   128
#define BM   128          // q tokens per block (4 waves x 32)
#define BN   64           // kv tokens per iteration
#define NKT  (LKV/BN)     // 8
// fallback-kernel params (first verified kernel)
#define KS_STR 132
#define VT_STR 68
#define PT_STR 68

// workspace layout (halves): K16[g 64][kt 8][chunk 1024][8] then V16t[g 64][kt 8][chunk 1024][8]
#define G_STRIDE 65536ull          // halves per g per tensor
#define WS_BYTES (2ull*64ull*G_STRIDE*2ull)   // 16,777,216 B

// LDS bank swizzle: s(r) = (r&3) | ((r&8)>>1). XOR-involution on the low 3 bits
// of the chunk index; 8 distinct values over every 16-lane read group for both
// access patterns (K rows R: swz3(R)=ln&7 pattern; V rows R=16dmt+ln).
__device__ inline int swz3(int r) { return (r & 3) | ((r & 8) >> 1); }

#define GLOAD16(gsrc, ldst) \
    __builtin_amdgcn_global_load_lds((const __attribute__((address_space(1))) void*)(gsrc), \
                                     (__attribute__((address_space(3))) void*)(ldst), 16, 0, 0)

// ---------------------------------------------------------------------------
// Pre-pass: K -> f16 (swz3-swizzled chunk order), V -> f16 transposed (swz3).
// Stored chunk c of row r holds logical chunk c ^ swz3(r); a LINEAR
// global_load_lds fill then yields an LDS image read conflict-free at
// byte = r*rowbytes + ((c ^ swz3(r))*16).
// ---------------------------------------------------------------------------
__global__ __launch_bounds__(256)
void prepack(const float* __restrict__ kg, const float* __restrict__ vg,
             f16* __restrict__ ws)
{
    __shared__ float vtile[64*132];            // f32 staging for V transpose
    const int tid = threadIdx.x;
    const int kt  = blockIdx.x;                // 0..7
    const int g   = blockIdx.y;                // 0..63  (slice offset = g*65536 floats)

    if (blockIdx.z == 0) {
        const float* kb = kg + (size_t)g*65536 + (size_t)kt*8192;  // [64][128] tile
        f16* kout = ws + (size_t)g*G_STRIDE + (size_t)kt*8192;
#pragma unroll
        for (int i = 0; i < 4; ++i) {
            int q = i*256 + tid;               // output chunk index 0..1023
            int r = q >> 4, c = q & 15;
            const float* src = kb + r*128 + ((c ^ swz3(r))*8);
            float4 a = *(const float4*)src;
            float4 b = *(const float4*)(src + 4);
            f16x8 h = { (f16)a.x,(f16)a.y,(f16)a.z,(f16)a.w,
                        (f16)b.x,(f16)b.y,(f16)b.z,(f16)b.w };
            *(f16x8*)(kout + (size_t)q*8) = h;
        }
    } else {
        const float* vb = vg + (size_t)g*65536 + (size_t)kt*8192;  // [64 kv][128 d]
        f16* vout = ws + 64ull*G_STRIDE + (size_t)g*G_STRIDE + (size_t)kt*8192;
#pragma unroll
        for (int i = 0; i < 8; ++i) {
            int f = tid + i*256;
            int row = f >> 5, c4 = f & 31;
            float4 x = *(const float4*)(vb + (size_t)f*4);
            *(float4*)(vtile + row*132 + c4*4) = x;
        }
        __syncthreads();
#pragma unroll
        for (int i = 0; i < 4; ++i) {
            int q = i*256 + tid;               // 0..1023
            int r = q >> 3, c = q & 7;         // r = d row (0..127), c = stored kv chunk
            int kv0 = (c ^ swz3(r))*8;
            f16x8 h;
#pragma unroll
            for (int j = 0; j < 8; ++j) h[j] = (f16)vtile[(kv0+j)*132 + r];
            *(f16x8*)(vout + (size_t)q*8) = h;
        }
    }
}

// ---------------------------------------------------------------------------
// Main flash-attention kernel (R6-verified structure + double-buffered K/V,
// one sync/iter, tree softmax, defer-max).
// kv-row permutation for the QK^T A-operand:
//   A-row m of tile mt  <->  kv = 32*(mt>>1) + 8*(m>>2) + 4*(mt&1) + (m&3)
// so S^T C/D elem (lane qd, tile mt, r) = P[q][kv=32*(mt>>1)+8*qd+4*(mt&1)+r]
// = PV B-operand slot j=4*(mt&1)+r of chunk kc2=mt>>1 -- in-lane, no LDS.
// Schedule: prologue stages tile 0 into buf0; each iter t issues tile t+1 into
// buf[cur^1] FIRST (hides a full iteration of latency), computes from buf[cur],
// then a single __syncthreads (drains DMA + ds_reads) and swaps.
// ---------------------------------------------------------------------------
__global__ __launch_bounds__(256, 3)
void fa_fwd(const float* __restrict__ qg, const f16* __restrict__ ws,
            float* __restrict__ og)
{
    __shared__ __align__(16) f16 Ks[2][BN*DD];    // 2 x 16384 B, swizzled
    __shared__ __align__(16) f16 Vt[2][DD*BN];    // 2 x 16384 B, swizzled

    const int tid  = threadIdx.x;
    const int wave = tid >> 6;
    const int lane = tid & 63;
    const int ln   = lane & 15;
    const int qd   = lane >> 4;

    // XCD-aware decode: all 16 q-blocks of a batch g share an XCD (bid%8 fixed).
    const int bid = blockIdx.x;                 // 0..1023
    const int qt  = (bid >> 3) & 15;
    const int g   = ((bid & 7) << 3) | (bid >> 7);
    const int bb  = g >> 5;
    const int lhi = g & 31;

    const float* qmat = qg + (size_t)(bb*LL + 64*lhi)*4096;  // [2048][128] f32
    const f16*   kw   = ws + (size_t)g*G_STRIDE;
    const f16*   vw   = ws + (64ull + (size_t)g)*G_STRIDE;

    const int qbase = qt*BM + wave*32;

    auto issueK = [&](int kt, int buf) {
#pragma unroll
        for (int i = 0; i < 4; ++i)
            GLOAD16(kw + (size_t)kt*8192 + (size_t)(i*256 + tid)*8,
                    &Ks[buf][(i*256 + wave*64)*8]);
    };
    auto issueV = [&](int kt, int buf) {
#pragma unroll
        for (int i = 0; i < 4; ++i)
            GLOAD16(vw + (size_t)kt*8192 + (size_t)(i*256 + tid)*8,
                    &Vt[buf][(i*256 + wave*64)*8]);
    };

    issueK(0, 0);
    issueV(0, 0);

    // Q fragments: B-operand of S^T=K*Q^T. frag(nt,kc) slot j = Q''[qbase+16nt+ln][32kc+8qd+j]
    f16x8 qf[2][4];
#pragma unroll
    for (int nt = 0; nt < 2; ++nt) {
        const float* qrow = qmat + (size_t)(qbase + 16*nt + ln)*DD;
#pragma unroll
        for (int kc = 0; kc < 4; ++kc) {
            const float4* qp = (const float4*)(qrow + kc*32 + 8*qd);
            float4 f0 = qp[0], f1 = qp[1];
            f16x8 t = { (f16)f0.x,(f16)f0.y,(f16)f0.z,(f16)f0.w,
                        (f16)f1.x,(f16)f1.y,(f16)f1.z,(f16)f1.w };
            qf[nt][kc] = t;
        }
    }

    f32x4 o[2][8];   // o[nt][dmt][r] = O^T[16*dmt+4*qd+r][q(nt)]
#pragma unroll
    for (int nt = 0; nt < 2; ++nt)
#pragma unroll
        for (int dmt = 0; dmt < 8; ++dmt)
#pragma unroll
            for (int r = 0; r < 4; ++r) o[nt][dmt][r] = 0.0f;

    float mrun[2] = {-1e30f, -1e30f}, lrun[2] = {0.0f, 0.0f};
    const float SC2 = 0.08837890625f * 1.44269504088896340f;  // fp16-rounded scale * log2(e)

    __syncthreads();    // drains vmcnt(0): K(0), V(0) landed

    int cur = 0;
#pragma unroll 1
    for (int t = 0; t < NKT; ++t) {
        // ---- issue next tile into the other buffer (full-iteration prefetch) ----
        if (t+1 < NKT) { issueK(t+1, cur^1); issueV(t+1, cur^1); }

        // ---- S^T = K*Q^T with permuted A-rows ----
        f32x4 st[2][4];
#pragma unroll
        for (int nt = 0; nt < 2; ++nt)
#pragma unroll
            for (int mt = 0; mt < 4; ++mt)
#pragma unroll
                for (int r = 0; r < 4; ++r) st[nt][mt][r] = 0.0f;
        __builtin_amdgcn_s_setprio(1);
#pragma unroll
        for (int mt = 0; mt < 4; ++mt) {
            const int R = 32*(mt >> 1) + 8*(ln >> 2) + 4*(mt & 1) + (ln & 3);
#pragma unroll
            for (int kc = 0; kc < 4; ++kc) {
                f16x8 af = *(const f16x8*)(&Ks[cur][R*DD + (((kc*4 + qd) ^ swz3(R))*8)]);
#pragma unroll
                for (int nt = 0; nt < 2; ++nt)
                    st[nt][mt] = __builtin_amdgcn_mfma_f32_16x16x32_f16(af, qf[nt][kc], st[nt][mt], 0,0,0);
            }
        }
        __builtin_amdgcn_s_setprio(0);

        // ---- online softmax: raw tree-max, defer-max (T13), fused fma+exp2 ----
        float alph[2];
        int skip[2];
#pragma unroll
        for (int nt = 0; nt < 2; ++nt) {
            // tree max over raw scores (SC2 > 0 commutes with max); v_max3-friendly
            float a = fmaxf(fmaxf(st[nt][0][0], st[nt][0][1]), fmaxf(st[nt][0][2], st[nt][0][3]));
            float b = fmaxf(fmaxf(st[nt][1][0], st[nt][1][1]), fmaxf(st[nt][1][2], st[nt][1][3]));
            float c = fmaxf(fmaxf(st[nt][2][0], st[nt][2][1]), fmaxf(st[nt][2][2], st[nt][2][3]));
            float d = fmaxf(fmaxf(st[nt][3][0], st[nt][3][1]), fmaxf(st[nt][3][2], st[nt][3][3]));
            float mx = fmaxf(fmaxf(a, b), fmaxf(c, d));
            mx = fmaxf(mx, __shfl_xor(mx, 16, 64));
            mx = fmaxf(mx, __shfl_xor(mx, 32, 64));
            float mxs = mx * SC2;
            // defer-max: if no q-row in this wave grew by >8 (log2), keep old max
            int s = __all(mxs - mrun[nt] <= 8.0f);
            if (s) {
                alph[nt] = 1.0f;
            } else {
                float mnew = fmaxf(mrun[nt], mxs);
                alph[nt] = exp2f(mrun[nt] - mnew);
                mrun[nt] = mnew;
            }
            skip[nt] = s;
            const float mm = mrun[nt];
            // p = exp2(raw*SC2 - mm), stored back for the in-lane PV operand
#pragma unroll
            for (int mt = 0; mt < 4; ++mt)
#pragma unroll
                for (int r = 0; r < 4; ++r)
                    st[nt][mt][r] = exp2f(__builtin_fmaf(st[nt][mt][r], SC2, -mm));
            // tree sum
            float s0 = (st[nt][0][0] + st[nt][0][1]) + (st[nt][0][2] + st[nt][0][3]);
            float s1 = (st[nt][1][0] + st[nt][1][1]) + (st[nt][1][2] + st[nt][1][3]);
            float s2 = (st[nt][2][0] + st[nt][2][1]) + (st[nt][2][2] + st[nt][2][3]);
            float s3 = (st[nt][3][0] + st[nt][3][1]) + (st[nt][3][2] + st[nt][3][3]);
            float rs = (s0 + s1) + (s2 + s3);
            rs += __shfl_xor(rs, 16, 64);
            rs += __shfl_xor(rs, 32, 64);
            lrun[nt] = __builtin_fmaf(lrun[nt], alph[nt], rs);
        }

        // ---- rescale O^T only when some row's max moved (wave-uniform branch) ----
        if (!(skip[0] & skip[1])) {
#pragma unroll
            for (int nt = 0; nt < 2; ++nt)
#pragma unroll
                for (int dmt = 0; dmt < 8; ++dmt)
#pragma unroll
                    for (int r = 0; r < 4; ++r) o[nt][dmt][r] *= alph[nt];
        }

        // ---- O^T += V^T * P^T : A = swizzled Vt rows, B = in-lane pf ----
#pragma unroll
        for (int kc2 = 0; kc2 < 2; ++kc2) {
            f16x8 pf[2];
#pragma unroll
            for (int nt = 0; nt < 2; ++nt) {
                f16x8 pp = { (f16)st[nt][2*kc2+0][0], (f16)st[nt][2*kc2+0][1],
                             (f16)st[nt][2*kc2+0][2], (f16)st[nt][2*kc2+0][3],
                             (f16)st[nt][2*kc2+1][0], (f16)st[nt][2*kc2+1][1],
                             (f16)st[nt][2*kc2+1][2], (f16)st[nt][2*kc2+1][3] };
                pf[nt] = pp;
            }
            __builtin_amdgcn_s_setprio(1);
#pragma unroll
            for (int dmt = 0; dmt < 8; ++dmt) {
                const int R = 16*dmt + ln;
                f16x8 vf = *(const f16x8*)(&Vt[cur][R*BN + (((kc2*4 + qd) ^ swz3(R))*8)]);
#pragma unroll
                for (int nt = 0; nt < 2; ++nt)
                    o[nt][dmt] = __builtin_amdgcn_mfma_f32_16x16x32_f16(vf, pf[nt], o[nt][dmt], 0,0,0);
            }
            __builtin_amdgcn_s_setprio(0);
        }

        // ---- single sync: all reads of buf[cur] retired; DMA for t+1 landed ----
        if (t+1 < NKT) { __syncthreads(); cur ^= 1; }
    }

    // ---- epilogue: O^T/l -> og[(bb*2048+t)*4096 + lhi*128 + d] ----
#pragma unroll
    for (int nt = 0; nt < 2; ++nt) {
        float inv = 1.0f / lrun[nt];
        int qtok = qbase + 16*nt + ln;
        float* orow = og + (size_t)(bb*LL + qtok)*4096 + lhi*DD + 4*qd;
#pragma unroll
        for (int dmt = 0; dmt < 8; ++dmt) {
            float4 x = { o[nt][dmt][0]*inv, o[nt][dmt][1]*inv,
                         o[nt][dmt][2]*inv, o[nt][dmt][3]*inv };
            *(float4*)(orow + 16*dmt) = x;
        }
    }
}

// ---------------------------------------------------------------------------
// Fallback (first verified kernel) for the case ws_size < WS_BYTES.
// ---------------------------------------------------------------------------
__global__ __launch_bounds__(256, 2)
void fa_fwd_fb(const float* __restrict__ qg,
               const float* __restrict__ kg,
               const float* __restrict__ vg,
               float* __restrict__ og)
{
    __shared__ __align__(16) f16 smem[BN*KS_STR + DD*VT_STR + BM*PT_STR];
    f16* Ks = smem;
    f16* Vt = smem + BN*KS_STR;
    f16* Pt = smem + BN*KS_STR + DD*VT_STR;

    const int tid  = threadIdx.x;
    const int wave = tid >> 6;
    const int lane = tid & 63;
    const int ln   = lane & 15;
    const int qd   = lane >> 4;

    const int qt   = blockIdx.x;
    const int g    = blockIdx.y;
    const int bb   = g >> 5;
    const int lhi  = g & 31;

    const float* qmat = qg + (size_t)(bb*LL + 64*lhi)*4096;
    const float* kmat = kg + (size_t)(bb*LL + 64*lhi)*1024;
    const float* vmat = vg + (size_t)(bb*LL + 64*lhi)*1024;

    const int qbase = qt*BM + wave*32;

    f16x8 qf[2][4];
#pragma unroll
    for (int nt = 0; nt < 2; ++nt) {
        const float* qrow = qmat + (size_t)(qbase + 16*nt + ln)*DD;
#pragma unroll
        for (int kc = 0; kc < 4; ++kc) {
            const float4* qp = (const float4*)(qrow + kc*32 + 8*qd);
            float4 f0 = qp[0], f1 = qp[1];
            f16x8 t = { (f16)f0.x,(f16)f0.y,(f16)f0.z,(f16)f0.w,
                        (f16)f1.x,(f16)f1.y,(f16)f1.z,(f16)f1.w };
            qf[nt][kc] = t;
        }
    }

    f32x4 o[2][8];
#pragma unroll
    for (int nt = 0; nt < 2; ++nt)
#pragma unroll
        for (int dmt = 0; dmt < 8; ++dmt)
#pragma unroll
            for (int r = 0; r < 4; ++r) o[nt][dmt][r] = 0.0f;

    float mrun[2] = {-1e30f, -1e30f}, lrun[2] = {0.0f, 0.0f};
    const float SC2 = 0.08837890625f * 1.44269504088896340f;

    for (int kt = 0; kt < LKV/BN; ++kt) {
        const float* kb = kmat + kt*BN*DD;
        const float* vb = vmat + kt*BN*DD;

#pragma unroll
        for (int i = 0; i < 8; ++i) {
            int f = tid + i*256;
            int row = f >> 5, c4 = f & 31;
            float4 x = *(const float4*)(kb + f*4);
            f16x4 h4 = { (f16)x.x,(f16)x.y,(f16)x.z,(f16)x.w };
            *(f16x4*)(Ks + row*KS_STR + c4*4) = h4;
        }
#pragma unroll
        for (int i = 0; i < 8; ++i) {
            int f = tid + i*256;
            int kvr = f & 63, c4 = f >> 6;
            float4 x = *(const float4*)(vb + (size_t)kvr*DD + c4*4);
            Vt[(c4*4+0)*VT_STR + kvr] = (f16)x.x;
            Vt[(c4*4+1)*VT_STR + kvr] = (f16)x.y;
            Vt[(c4*4+2)*VT_STR + kvr] = (f16)x.z;
            Vt[(c4*4+3)*VT_STR + kvr] = (f16)x.w;
        }
        __syncthreads();

        f32x4 st[2][4];
#pragma unroll
        for (int nt = 0; nt < 2; ++nt)
#pragma unroll
            for (int mt = 0; mt < 4; ++mt)
#pragma unroll
                for (int r = 0; r < 4; ++r) st[nt][mt][r] = 0.0f;
#pragma unroll
        for (int mt = 0; mt < 4; ++mt) {
            const f16* kr = Ks + (16*mt + ln)*KS_STR + 8*qd;
#pragma unroll
            for (int kc = 0; kc < 4; ++kc) {
                f16x4 a0 = *(const f16x4*)(kr + kc*32);
                f16x4 a1 = *(const f16x4*)(kr + kc*32 + 4);
                f16x8 af = __builtin_shufflevector(a0, a1, 0,1,2,3,4,5,6,7);
#pragma unroll
                for (int nt = 0; nt < 2; ++nt)
                    st[nt][mt] = __builtin_amdgcn_mfma_f32_16x16x32_f16(af, qf[nt][kc], st[nt][mt], 0,0,0);
            }
        }

        float alph[2];
#pragma unroll
        for (int nt = 0; nt < 2; ++nt) {
            float mx = -1e30f;
#pragma unroll
            for (int mt = 0; mt < 4; ++mt)
#pragma unroll
                for (int r = 0; r < 4; ++r) {
                    float v = st[nt][mt][r]*SC2; st[nt][mt][r] = v; mx = fmaxf(mx, v);
                }
            mx = fmaxf(mx, __shfl_xor(mx, 16, 64));
            mx = fmaxf(mx, __shfl_xor(mx, 32, 64));
            float mnew = fmaxf(mrun[nt], mx);
            alph[nt] = exp2f(mrun[nt] - mnew);
            float rs = 0.0f;
#pragma unroll
            for (int mt = 0; mt < 4; ++mt)
#pragma unroll
                for (int r = 0; r < 4; ++r) {
                    float p = exp2f(st[nt][mt][r] - mnew);
                    st[nt][mt][r] = p; rs += p;
                }
            rs += __shfl_xor(rs, 16, 64);
            rs += __shfl_xor(rs, 32, 64);
            lrun[nt] = lrun[nt]*alph[nt] + rs;
            mrun[nt] = mnew;
        }

#pragma unroll
        for (int nt = 0; nt < 2; ++nt) {
            f16* prow = Pt + (wave*32 + 16*nt + ln)*PT_STR + 4*qd;
#pragma unroll
            for (int mt = 0; mt < 4; ++mt)
#pragma unroll
                for (int p2 = 0; p2 < 2; ++p2) {
                    f16x2 pp = { (f16)st[nt][mt][2*p2], (f16)st[nt][mt][2*p2+1] };
                    *(f16x2*)(prow + 16*mt + 2*p2) = pp;
                }
        }

#pragma unroll
        for (int nt = 0; nt < 2; ++nt)
#pragma unroll
            for (int dmt = 0; dmt < 8; ++dmt)
#pragma unroll
                for (int r = 0; r < 4; ++r) o[nt][dmt][r] *= alph[nt];

#pragma unroll
        for (int kc2 = 0; kc2 < 2; ++kc2) {
            f16x8 pf[2];
#pragma unroll
            for (int nt = 0; nt < 2; ++nt) {
                const f16* pr = Pt + (wave*32 + 16*nt + ln)*PT_STR + kc2*32 + 8*qd;
                f16x4 b0 = *(const f16x4*)(pr);
                f16x4 b1 = *(const f16x4*)(pr + 4);
                pf[nt] = __builtin_shufflevector(b0, b1, 0,1,2,3,4,5,6,7);
            }
#pragma unroll
            for (int dmt = 0; dmt < 8; ++dmt) {
                const f16* vr = Vt + (16*dmt + ln)*VT_STR + kc2*32 + 8*qd;
                f16x4 a0 = *(const f16x4*)(vr);
                f16x4 a1 = *(const f16x4*)(vr + 4);
                f16x8 vf = __builtin_shufflevector(a0, a1, 0,1,2,3,4,5,6,7);
#pragma unroll
                for (int nt = 0; nt < 2; ++nt)
                    o[nt][dmt] = __builtin_amdgcn_mfma_f32_16x16x32_f16(vf, pf[nt], o[nt][dmt], 0,0,0);
            }
        }
        __syncthreads();
    }

#pragma unroll
    for (int nt = 0; nt < 2; ++nt) {
        float inv = 1.0f / lrun[nt];
        int qtok = qbase + 16*nt + ln;
        float* orow = og + (size_t)(bb*LL + qtok)*4096 + lhi*DD + 4*qd;
#pragma unroll
        for (int dmt = 0; dmt < 8; ++dmt) {
            float4 x = { o[nt][dmt][0]*inv, o[nt][dmt][1]*inv,
                         o[nt][dmt][2]*inv, o[nt][dmt][3]*inv };
            *(float4*)(orow + 16*dmt) = x;
        }
    }
}

extern "C" void kernel_launch(void* const* d_in, const int* in_sizes, int n_in,
                              void* d_out, int out_size, void* d_ws, size_t ws_size,
                              hipStream_t stream) {
    (void)in_sizes; (void)n_in; (void)out_size;
    const float* q = (const float*)d_in[0];
    const float* k = (const float*)d_in[1];
    const float* v = (const float*)d_in[2];
    float* o = (float*)d_out;
    if (d_ws != nullptr && ws_size >= (size_t)WS_BYTES) {
        hipLaunchKernelGGL(prepack, dim3(8, 64, 2), dim3(256), 0, stream,
                           k, v, (f16*)d_ws);
        hipLaunchKernelGGL(fa_fwd, dim3(1024), dim3(256), 0, stream,
                           q, (const f16*)d_ws, o);
    } else {
        hipLaunchKernelGGL(fa_fwd_fb, dim3(LQ/BM, 64), dim3(256), 0, stream,
                           q, k, v, o);
    }
}